// Round 1
// baseline (337.301 us; speedup 1.0000x reference)
//
#include <hip/hip_runtime.h>
#include <hip/hip_bf16.h>

#define B_ 8
#define N_ 1024
#define DIN 256
#define DOUT 256
#define R_ 4

typedef __attribute__((ext_vector_type(8))) short bf16x8;
typedef __attribute__((ext_vector_type(4))) float f32x4;
typedef __attribute__((ext_vector_type(4))) int i32x4;

__device__ __forceinline__ unsigned short f2bf(float f) {
    union { float f; unsigned int u; } v; v.f = f;
    unsigned int u = v.u;
    u += 0x7fffu + ((u >> 16) & 1u);
    return (unsigned short)(u >> 16);
}
__device__ __forceinline__ float bf2f(unsigned short h) {
    union { float f; unsigned int u; } v; v.u = ((unsigned int)h) << 16;
    return v.f;
}

// ---------------- k0: convert rel_w (R*256*256 f32) to bf16 ----------------
__global__ void k0_cvt_relw(const float* __restrict__ rw,
                            unsigned short* __restrict__ rwb) {
    int t = blockIdx.x * blockDim.x + threadIdx.x;  // 0..65535 (float4 units)
    float4 v = ((const float4*)rw)[t];
    ushort4 o;
    o.x = f2bf(v.x); o.y = f2bf(v.y); o.z = f2bf(v.z); o.w = f2bf(v.w);
    ((ushort4*)rwb)[t] = o;
}

// ---------------- k1: feats^T[b,r,d,n] = (node[b] @ rel_w[r]^T + rel_b)^T ---
// grid 512 = (b,r,nt), 256 threads = 4 waves, wave = 16 rows of n.
__global__ __launch_bounds__(256) void k1_proj(const float* __restrict__ node,
        const unsigned short* __restrict__ rwb, const float* __restrict__ rel_b,
        unsigned short* __restrict__ featsT) {
    int bid = blockIdx.x;
    int nt = bid & 15, r = (bid >> 4) & 3, b = bid >> 6;
    int wave = threadIdx.x >> 6, lane = threadIdx.x & 63;
    int m = lane & 15, q = lane >> 4;
    int n0 = nt * 64 + wave * 16;

    const float* Abase = node + ((b * N_ + n0 + m) * DIN) + q * 8;
    const unsigned short* Bbase = rwb + ((r * DOUT + m) * DIN) + q * 8;

    f32x4 acc[16];
#pragma unroll
    for (int i = 0; i < 16; i++) acc[i] = (f32x4)0.0f;

    for (int k = 0; k < DIN; k += 32) {
        float4 a0 = *(const float4*)(Abase + k);
        float4 a1 = *(const float4*)(Abase + k + 4);
        bf16x8 af;
        af[0] = (short)f2bf(a0.x); af[1] = (short)f2bf(a0.y);
        af[2] = (short)f2bf(a0.z); af[3] = (short)f2bf(a0.w);
        af[4] = (short)f2bf(a1.x); af[5] = (short)f2bf(a1.y);
        af[6] = (short)f2bf(a1.z); af[7] = (short)f2bf(a1.w);
#pragma unroll
        for (int nb = 0; nb < 16; nb++) {
            bf16x8 bf = *(const bf16x8*)(Bbase + nb * 16 * DIN + k);
            acc[nb] = __builtin_amdgcn_mfma_f32_16x16x32_bf16(af, bf, acc[nb], 0, 0, 0);
        }
    }
#pragma unroll
    for (int nb = 0; nb < 16; nb++) {
        int d = nb * 16 + m;
        float bias = rel_b[r * DOUT + d];
        ushort4 o;
        o.x = f2bf(acc[nb][0] + bias);
        o.y = f2bf(acc[nb][1] + bias);
        o.z = f2bf(acc[nb][2] + bias);
        o.w = f2bf(acc[nb][3] + bias);
        *(ushort4*)(featsT + (((b * R_ + r) * DOUT + d) * N_) + n0 + q * 4) = o;
    }
}

// ---------------- k2: e[b,r,n] = exp( sum_d featsT[d][n] * attn_w[256+d] ) --
__global__ __launch_bounds__(256) void k2_e(const unsigned short* __restrict__ featsT,
        const float* __restrict__ attn_w, float* __restrict__ e) {
    int bid = blockIdx.x;  // 128
    int t = threadIdx.x;
    int nb4 = bid & 3, r = (bid >> 2) & 3, b = bid >> 4;
    int n = nb4 * 256 + t;
    const unsigned short* base = featsT + ((b * R_ + r) * DOUT) * N_ + n;
    float acc = 0.f;
#pragma unroll 4
    for (int d = 0; d < DOUT; d++) acc += bf2f(base[d * N_]) * attn_w[DOUT + d];
    e[(b * R_ + r) * N_ + n] = __expf(acc);
}

// ---------------- k3: per-(b,r) masked softmax @ feats -> aggp[b,r,n,d] ----
// grid 512 = (b,r,it), it = 64-row i-tile; 4 waves x 16 rows.
__global__ __launch_bounds__(256) void k3_attn(const int* __restrict__ adj,
        const unsigned short* __restrict__ featsT, const float* __restrict__ e,
        float* __restrict__ aggp) {
    __shared__ unsigned short Btile[256 * 40];  // [d][j_local], pad 32->40
    int bid = blockIdx.x;
    int it = bid & 15, r = (bid >> 4) & 3, b = bid >> 6;
    int t = threadIdx.x;
    int lane = t & 63, wave = t >> 6;
    int m = lane & 15, q = lane >> 4;
    int i0 = it * 64 + wave * 16;

    const int* adjbase = adj + (((b * R_ + r) * N_) + i0 + m) * (long)N_ + q * 8;
    const float* ebase = e + (b * R_ + r) * N_ + q * 8;
    const unsigned short* ftbase = featsT + ((b * R_ + r) * DOUT) * N_;

    f32x4 acc[16];
#pragma unroll
    for (int i = 0; i < 16; i++) acc[i] = (f32x4)0.0f;
    float l = 0.f;

    for (int jb = 0; jb < N_; jb += 32) {
        __syncthreads();
#pragma unroll
        for (int itn = 0; itn < 4; itn++) {
            int idx = itn * 256 + t;
            int row = idx >> 2, ch = idx & 3;
            bf16x8 v = *(const bf16x8*)(ftbase + row * N_ + jb + ch * 8);
            *(bf16x8*)(&Btile[row * 40 + ch * 8]) = v;
        }
        __syncthreads();

        i32x4 ad0 = *(const i32x4*)(adjbase + jb);
        i32x4 ad1 = *(const i32x4*)(adjbase + jb + 4);
        float4 e0 = *(const float4*)(ebase + jb);
        float4 e1 = *(const float4*)(ebase + jb + 4);
        int av[8] = {ad0.x, ad0.y, ad0.z, ad0.w, ad1.x, ad1.y, ad1.z, ad1.w};
        float ev[8] = {e0.x, e0.y, e0.z, e0.w, e1.x, e1.y, e1.z, e1.w};
        bf16x8 af;
#pragma unroll
        for (int jj = 0; jj < 8; jj++) {
            bool on = (av[jj] != 0);
            af[jj] = on ? (short)f2bf(ev[jj]) : (short)0;
            l += on ? ev[jj] : 0.f;
        }
#pragma unroll
        for (int nb = 0; nb < 16; nb++) {
            bf16x8 bfq = *(const bf16x8*)(&Btile[(nb * 16 + m) * 40 + q * 8]);
            acc[nb] = __builtin_amdgcn_mfma_f32_16x16x32_bf16(af, bfq, acc[nb], 0, 0, 0);
        }
    }

    // row-sum l: lanes {m, m+16, m+32, m+48} hold partial sums of row m
    l += __shfl_xor(l, 16, 64);
    l += __shfl_xor(l, 32, 64);
    float invl = (l > 0.f) ? 1.0f / l : 0.f;
    float invr[4];
#pragma unroll
    for (int reg = 0; reg < 4; reg++)
        invr[reg] = __shfl(invl, (lane >> 4) * 4 + reg, 64);

#pragma unroll
    for (int nb = 0; nb < 16; nb++) {
        int d = nb * 16 + m;
        float* outp = aggp + (((long)(b * R_ + r) * N_) + i0 + q * 4) * DOUT + d;
#pragma unroll
        for (int reg = 0; reg < 4; reg++)
            outp[reg * DOUT] = acc[nb][reg] * invr[reg];
    }
}

// ---------------- k4: out = sigmoid((sum_r aggp)·gw + gb) * sum_r aggp ------
__global__ __launch_bounds__(256) void k4_out(const float* __restrict__ aggp,
        const float* __restrict__ gate_w, const float* __restrict__ gate_b,
        float* __restrict__ out) {
    __shared__ float red[4];
    int bid = blockIdx.x;  // 8192 = b*1024 + n
    int n = bid & 1023, b = bid >> 10;
    int d = threadIdx.x;
    float s = 0.f;
#pragma unroll
    for (int r = 0; r < R_; r++)
        s += aggp[(((long)(b * R_ + r) * N_) + n) * DOUT + d];
    float v = s * gate_w[d];
#pragma unroll
    for (int off = 32; off; off >>= 1) v += __shfl_down(v, off, 64);
    int lane = d & 63, wave = d >> 6;
    if (lane == 0) red[wave] = v;
    __syncthreads();
    float tot = red[0] + red[1] + red[2] + red[3];
    float g = 1.f / (1.f + __expf(-(tot + gate_b[0])));
    out[((long)(b * N_ + n)) * DOUT + d] = g * s;
}

extern "C" void kernel_launch(void* const* d_in, const int* in_sizes, int n_in,
                              void* d_out, int out_size, void* d_ws, size_t ws_size,
                              hipStream_t stream) {
    const float* node   = (const float*)d_in[0];
    const int*   adj    = (const int*)d_in[1];
    const float* rel_w  = (const float*)d_in[2];
    const float* rel_b  = (const float*)d_in[3];
    const float* attn_w = (const float*)d_in[4];
    // d_in[5] = attn_b: cancels in softmax, unused
    const float* gate_w = (const float*)d_in[6];
    const float* gate_b = (const float*)d_in[7];
    float* out = (float*)d_out;

    char* ws = (char*)d_ws;
    unsigned short* relwb  = (unsigned short*)ws;                       // 524,288 B
    unsigned short* featsT = (unsigned short*)(ws + 524288);            // 16,777,216 B
    float*          e      = (float*)(ws + 524288 + 16777216);          // 131,072 B
    float*          aggp   = (float*)(ws + 524288 + 16777216 + 131072); // 33,554,432 B

    k0_cvt_relw<<<256, 256, 0, stream>>>(rel_w, relwb);
    k1_proj<<<512, 256, 0, stream>>>(node, relwb, rel_b, featsT);
    k2_e<<<128, 256, 0, stream>>>(featsT, attn_w, e);
    k3_attn<<<512, 256, 0, stream>>>(adj, featsT, e, aggp);
    k4_out<<<8192, 256, 0, stream>>>(aggp, gate_w, gate_b, out);
}